// Round 1
// baseline (859.564 us; speedup 1.0000x reference)
//
#include <hip/hip_runtime.h>
#include <hip/hip_bf16.h>
#include <stdint.h>

// Problem constants
#define BTOT 65536
#define KAUG 320
#define NBIG 2176
#define NBIG_PAD 2304
#define OUTD 384

typedef __attribute__((ext_vector_type(8))) short s16x8;
typedef __attribute__((ext_vector_type(4))) float f32x4;
typedef __attribute__((ext_vector_type(4))) uint32_t u32x4;

// workspace layout (bytes)
#define WS_WGT   0u                    // bf16 [512][64]   g-weights transposed [N][K]
#define WS_WFC   (64u*1024u)           // bf16 [256][320]  fc1 augmented, transposed
#define WS_WBIG  (224u*1024u)          // bf16 [2304][320] big augmented, transposed (padded rows zero)
#define WS_C1    (1664u*1024u)         // f32 [256]
#define WS_C2    (1665u*1024u)         // f32 [2304]
#define WS_ACT   (2u*1024u*1024u)      // bf16 [65536][320]  t_aug -> u_aug in place
#define WS_G2    (44u*1024u*1024u)     // bf16 [65536][256]

__device__ __forceinline__ float bs2f(short s) {
    uint32_t u = ((uint32_t)(uint16_t)s) << 16; float f; __builtin_memcpy(&f, &u, 4); return f;
}
__device__ __forceinline__ short f2bs(float f) {
    __hip_bfloat16 h = __float2bfloat16(f); short s; __builtin_memcpy(&s, &h, 2); return s;
}
// XOR swizzle on byte offset within a row (row byte stride must be a multiple of 128; kb 16B-aligned)
__device__ __forceinline__ uint32_t swz(uint32_t row, uint32_t kb) { return kb ^ ((row & 7u) << 4); }

__device__ __forceinline__ f32x4 mfma16(s16x8 a, s16x8 b, f32x4 c) {
    asm volatile("v_mfma_f32_16x16x32_bf16 %0, %1, %2, %0" : "+v"(c) : "v"(a), "v"(b));
    return c;
}

// ---------------- weight prep ----------------
// WgT[n][k]: n<256 -> film1_w[k][n] (g1), n>=256 -> film2_w[k][n-256] (g2)
__global__ __launch_bounds__(256) void k0a(const float* __restrict__ f1w, const float* __restrict__ f2w, char* ws) {
    int idx = blockIdx.x * 256 + threadIdx.x;   // 32768
    int n = idx >> 6, k = idx & 63;
    float v = (n < 256) ? f1w[k * 512 + n] : f2w[k * 512 + (n - 256)];
    ((short*)(ws + WS_WGT))[n * 64 + k] = f2bs(v);
}

// WfcT_aug[n][k]: k<256 -> fc1[k][n]; k>=256 -> sum_j film1_w[k-256][256+j]*fc1[j][n]. c1[n]=film1_b[256:]@fc1[:,n]
__global__ __launch_bounds__(320) void k0b(const float* __restrict__ f1w, const float* __restrict__ f1b,
                                           const float* __restrict__ fc1, char* ws) {
    int n = blockIdx.x, k = threadIdx.x;
    float v;
    if (k < 256) v = fc1[k * 256 + n];
    else { int r = k - 256; float s = 0.f;
        for (int j = 0; j < 256; ++j) s += f1w[r * 512 + 256 + j] * fc1[j * 256 + n];
        v = s; }
    ((short*)(ws + WS_WFC))[n * 320 + k] = f2bs(v);
    if (k == 0) { float s = 0.f;
        for (int j = 0; j < 256; ++j) s += f1b[256 + j] * fc1[j * 256 + n];
        ((float*)(ws + WS_C1))[n] = s; }
}

// WbigT_aug[n][k], n in [0,2304): Wbig col n (inv|wemb); k>=256 -> film2 b-part folded. Pad rows zero. c2 likewise.
__global__ __launch_bounds__(320) void k0c(const float* __restrict__ f2w, const float* __restrict__ f2b,
                                           const float* __restrict__ invw, const float* __restrict__ wemb, char* ws) {
    int n = blockIdx.x, k = threadIdx.x;
    float v = 0.f;
    if (n < NBIG) {
        if (k < 256) v = (n < 128) ? invw[k * 128 + n] : wemb[k * 2048 + (n - 128)];
        else { int r = k - 256; float s = 0.f;
            for (int j = 0; j < 256; ++j) {
                float wb = (n < 128) ? invw[j * 128 + n] : wemb[j * 2048 + (n - 128)];
                s += f2w[r * 512 + 256 + j] * wb; }
            v = s; }
    }
    ((short*)(ws + WS_WBIG))[n * 320 + k] = f2bs(v);
    if (k == 0) { float s = 0.f;
        if (n < NBIG) for (int j = 0; j < 256; ++j) {
            float wb = (n < 128) ? invw[j * 128 + n] : wemb[j * 2048 + (n - 128)];
            s += f2b[256 + j] * wb; }
        ((float*)(ws + WS_C2))[n] = s; }
}

// ---------------- A1: g = cond@Wg (K=64), FiLM1, write t_aug + g2 ----------------
__global__ __launch_bounds__(256) void a1(const float* __restrict__ feat, const float* __restrict__ cond,
                                          const float* __restrict__ f1b, const float* __restrict__ f2b, char* ws) {
    __shared__ short sA[64 * 64];     // cond tile, ROWB=128
    __shared__ short sB[512 * 64];    // WgT,      ROWB=128
    const int tid = threadIdx.x;
    const int r0 = blockIdx.x * 64;
    short* actw = (short*)(ws + WS_ACT);
    short* g2w  = (short*)(ws + WS_G2);

    // stage cond -> sA (swizzled) and dual-store bf16 cond into act cols 256..319
    for (int i = 0; i < 2; ++i) {
        int gid = tid + i * 256;            // 512 granules of 16B
        int row = gid >> 3, g = gid & 7;
        const float* src = cond + (size_t)(r0 + row) * 64 + g * 8;
        s16x8 p;
        for (int j = 0; j < 8; ++j) p[j] = f2bs(src[j]);
        *(s16x8*)((char*)sA + row * 128 + swz(row, g * 16)) = p;
        *(s16x8*)(actw + (size_t)(r0 + row) * 320 + 256 + g * 8) = p;
    }
    // stage WgT -> sB
    const char* wgt = ws + WS_WGT;
    for (int i = 0; i < 16; ++i) {
        int gid = tid + i * 256;            // 4096 granules
        int row = gid >> 3, g = gid & 7;
        u32x4 v = *(const u32x4*)(wgt + row * 128 + g * 16);
        *(u32x4*)((char*)sB + row * 128 + swz(row, g * 16)) = v;
    }
    __syncthreads();

    const int w = tid >> 6, l = tid & 63, lr = l & 15, lk = l >> 4;
    s16x8 af[4][2];
    for (int fm = 0; fm < 4; ++fm)
        for (int ks = 0; ks < 2; ++ks) {
            int row = fm * 16 + lr; uint32_t kb = (ks * 32 + lk * 8) * 2;
            af[fm][ks] = *(const s16x8*)((char*)sA + row * 128 + swz(row, kb));
        }

    for (int h = 0; h < 2; ++h) {
        int nw = w * 128 + h * 64;          // global g-col base for this wave-half
        f32x4 acc[4][4] = {};
        for (int ks = 0; ks < 2; ++ks) {
            uint32_t kb = (ks * 32 + lk * 8) * 2;
            s16x8 bf[4];
            for (int fn = 0; fn < 4; ++fn) {
                int row = nw + fn * 16 + lr;
                bf[fn] = *(const s16x8*)((char*)sB + row * 128 + swz(row, kb));
            }
            for (int fm = 0; fm < 4; ++fm)
                for (int fn = 0; fn < 4; ++fn)
                    acc[fm][fn] = mfma16(af[fm][ks], bf[fn], acc[fm][fn]);
        }
        asm volatile("s_nop 7\n\ts_nop 7" ::: );
        if (nw < 256) {   // g1 -> t
            for (int fm = 0; fm < 4; ++fm)
                for (int fn = 0; fn < 4; ++fn) {
                    int c = nw + fn * 16 + lr;
                    float bias = f1b[c];
                    for (int ri = 0; ri < 4; ++ri) {
                        int grow = r0 + fm * 16 + lk * 4 + ri;
                        float g1 = acc[fm][fn][ri] + bias;
                        float t = feat[(size_t)grow * 512 + c] * g1;
                        actw[(size_t)grow * 320 + c] = f2bs(t);
                    }
                }
        } else {          // g2 store
            for (int fm = 0; fm < 4; ++fm)
                for (int fn = 0; fn < 4; ++fn) {
                    int c = nw + fn * 16 + lr - 256;
                    float bias = f2b[c];
                    for (int ri = 0; ri < 4; ++ri) {
                        int grow = r0 + fm * 16 + lk * 4 + ri;
                        g2w[(size_t)grow * 256 + c] = f2bs(acc[fm][fn][ri] + bias);
                    }
                }
        }
    }
}

// ---------------- A2: s = t_aug @ WfcT_aug (K=320), u = (s + c1) * g2, in-place into act ----------------
__global__ __launch_bounds__(256) void a2(char* ws) {
    __shared__ short sA[64 * 64];
    __shared__ short sB[256 * 64];
    const int tid = threadIdx.x;
    const int r0 = blockIdx.x * 64;
    short* actw = (short*)(ws + WS_ACT);
    const char* wfc = ws + WS_WFC;
    const float* c1 = (const float*)(ws + WS_C1);
    const short* g2w = (const short*)(ws + WS_G2);
    const int w = tid >> 6, l = tid & 63, lr = l & 15, lk = l >> 4;
    f32x4 acc[4][4] = {};

    for (int kc = 0; kc < 5; ++kc) {
        __syncthreads();
        for (int i = 0; i < 2; ++i) {       // 512 granules A-chunk
            int gid = tid + i * 256; int row = gid >> 3, g = gid & 7;
            u32x4 v = *(const u32x4*)(actw + (size_t)(r0 + row) * 320 + kc * 64 + g * 8);
            *(u32x4*)((char*)sA + row * 128 + swz(row, g * 16)) = v;
        }
        for (int i = 0; i < 8; ++i) {       // 2048 granules B-chunk
            int gid = tid + i * 256; int row = gid >> 3, g = gid & 7;
            u32x4 v = *(const u32x4*)(wfc + (size_t)row * 640 + kc * 128 + g * 16);
            *(u32x4*)((char*)sB + row * 128 + swz(row, g * 16)) = v;
        }
        __syncthreads();
        for (int ks = 0; ks < 2; ++ks) {
            uint32_t kb = (ks * 32 + lk * 8) * 2;
            s16x8 af[4], bf[4];
            for (int fm = 0; fm < 4; ++fm) { int row = fm * 16 + lr;
                af[fm] = *(const s16x8*)((char*)sA + row * 128 + swz(row, kb)); }
            for (int fn = 0; fn < 4; ++fn) { int row = w * 64 + fn * 16 + lr;
                bf[fn] = *(const s16x8*)((char*)sB + row * 128 + swz(row, kb)); }
            for (int fm = 0; fm < 4; ++fm)
                for (int fn = 0; fn < 4; ++fn)
                    acc[fm][fn] = mfma16(af[fm], bf[fn], acc[fm][fn]);
        }
    }
    asm volatile("s_nop 7\n\ts_nop 7" ::: );
    for (int fm = 0; fm < 4; ++fm)
        for (int fn = 0; fn < 4; ++fn) {
            int c = w * 64 + fn * 16 + lr;
            float cc1 = c1[c];
            for (int ri = 0; ri < 4; ++ri) {
                int grow = r0 + fm * 16 + lk * 4 + ri;
                float s = acc[fm][fn][ri] + cc1;
                float u = s * bs2f(g2w[(size_t)grow * 256 + c]);
                actw[(size_t)grow * 320 + c] = f2bs(u);
            }
        }
}

// ---------------- B: out_all = u_aug @ WbigT_aug (K=320, N=2304 padded) + fused einsum ----------------
__global__ __launch_bounds__(512) void kb(const float* __restrict__ feat, char* ws, float* __restrict__ out) {
    __shared__ short sA[64 * 320];        // ROWB 640, full K resident
    __shared__ short sB[2][256 * 64];     // ROWB 128, double-buffered chunks
    __shared__ short sW[64 * 256];        // ROWB 512, w-tile for einsum
    const int tid = threadIdx.x;
    const int r0 = blockIdx.x * 64;
    const short* actw = (const short*)(ws + WS_ACT);
    const char* wbig = ws + WS_WBIG;
    const float* c2 = (const float*)(ws + WS_C2);

    // einsum persistent state: thread -> (row er, slot) ; slots 0..2 = y1 d, 3..7 = y2 d
    const int er = tid >> 3, slot = tid & 7;
    const int region = (slot < 3) ? 1 : 2;
    const int d = (slot < 3) ? slot : slot - 3;
    float y[32];
    float x[32];
    {
        const float* xb = feat + (size_t)(r0 + er) * 512 + 256 + ((region == 1) ? 0 : 96);
        const int stride = (region == 1) ? 3 : 5;
        for (int i = 0; i < 32; ++i) x[i] = xb[i * stride + d];
        for (int o = 0; o < 32; ++o) y[o] = 0.f;
    }

    // stage full A (2560 granules, 5/thread)
    for (int i = 0; i < 5; ++i) {
        int gid = tid + i * 512; int row = gid / 40, g = gid % 40;
        u32x4 v = *(const u32x4*)(actw + (size_t)(r0 + row) * 320 + g * 8);
        *(u32x4*)((char*)sA + row * 640 + swz(row, g * 16)) = v;
    }

    const int w = tid >> 6, l = tid & 63, lr = l & 15, lk = l >> 4;
    const int wm = w >> 2, wn = w & 3;    // wave tile: rows wm*32..+32, cols wn*64..+64 within N-tile of 256
    const float norm = 0.17677669529663687f;

    auto stageB = [&](int n0_, int kc_, int buf_) {
        for (int i = 0; i < 4; ++i) {
            int gid = tid + i * 512; int row = gid >> 3, g = gid & 7;
            int gn = n0_ + row;           // < 2304 (padded)
            u32x4 v = *(const u32x4*)(wbig + (size_t)gn * 640 + kc_ * 128 + g * 16);
            *(u32x4*)((char*)sB[buf_] + row * 128 + swz(row, g * 16)) = v;
        }
    };

    for (int nt = 0; nt < 9; ++nt) {
        const int n0 = nt * 256;
        f32x4 acc[2][4] = {};
        for (int kc = 0; kc < 5; ++kc) {
            if (kc == 0) { stageB(n0, 0, 0); __syncthreads(); }
            if (kc < 4) stageB(n0, kc + 1, (kc + 1) & 1);
            const char* bbuf = (const char*)sB[kc & 1];
            for (int ks = 0; ks < 2; ++ks) {
                uint32_t kb = (ks * 32 + lk * 8) * 2;
                s16x8 af[2], bf[4];
                for (int fm = 0; fm < 2; ++fm) { int row = wm * 32 + fm * 16 + lr;
                    af[fm] = *(const s16x8*)((char*)sA + row * 640 + swz(row, kc * 128 + kb)); }
                for (int fn = 0; fn < 4; ++fn) { int row = wn * 64 + fn * 16 + lr;
                    bf[fn] = *(const s16x8*)(bbuf + row * 128 + swz(row, kb)); }
                for (int fm = 0; fm < 2; ++fm)
                    for (int fn = 0; fn < 4; ++fn)
                        acc[fm][fn] = mfma16(af[fm], bf[fn], acc[fm][fn]);
            }
            __syncthreads();
        }
        asm volatile("s_nop 7\n\ts_nop 7" ::: );
        // epilogue: scalar cols -> out directly, w cols -> sW (+c2), pad cols dropped
        for (int fm = 0; fm < 2; ++fm)
            for (int fn = 0; fn < 4; ++fn) {
                int c = n0 + wn * 64 + fn * 16 + lr;
                float cc2 = c2[c];
                for (int ri = 0; ri < 4; ++ri) {
                    int rl = wm * 32 + fm * 16 + lk * 4 + ri;
                    float v = acc[fm][fn][ri] + cc2;
                    if (c < 128) out[(size_t)(r0 + rl) * OUTD + c] = v;
                    else if (c < NBIG) {
                        int cl = wn * 64 + fn * 16 + lr;
                        *(short*)((char*)sW + rl * 512 + ((uint32_t)(cl * 2) ^ ((rl & 7u) << 4))) = f2bs(v);
                    }
                }
            }
        __syncthreads();
        // fused einsum on this tile's w columns
        for (int islot = 0; islot < 8; ++islot) {
            int cb = n0 + islot * 32;
            if (cb < 128 || cb >= NBIG) continue;
            int treg = (cb < 1152) ? 1 : 2;
            if (treg != region) continue;
            int i = (cb - ((treg == 1) ? 128 : 1152)) >> 5;
            float xv = x[i];
            for (int og = 0; og < 4; ++og) {
                uint32_t clb = (uint32_t)(islot * 64 + og * 16);
                s16x8 wv = *(const s16x8*)((const char*)sW + er * 512 + (clb ^ ((er & 7u) << 4)));
                for (int j = 0; j < 8; ++j) y[og * 8 + j] += bs2f(wv[j]) * xv;
            }
        }
        __syncthreads();
    }
    // final equivariant writes
    float* orow = out + (size_t)(r0 + er) * OUTD;
    if (region == 1) { for (int o = 0; o < 32; ++o) orow[128 + o * 3 + d] = y[o] * norm; }
    else             { for (int o = 0; o < 32; ++o) orow[224 + o * 5 + d] = y[o] * norm; }
}

extern "C" void kernel_launch(void* const* d_in, const int* in_sizes, int n_in,
                              void* d_out, int out_size, void* d_ws, size_t ws_size,
                              hipStream_t stream) {
    (void)in_sizes; (void)n_in; (void)out_size; (void)ws_size;
    const float* feat = (const float*)d_in[0];
    const float* cond = (const float*)d_in[1];
    const float* f1w  = (const float*)d_in[2];
    const float* f1b  = (const float*)d_in[3];
    const float* fc1  = (const float*)d_in[4];
    const float* f2w  = (const float*)d_in[5];
    const float* f2b  = (const float*)d_in[6];
    const float* invw = (const float*)d_in[7];
    const float* wemb = (const float*)d_in[8];
    char* ws = (char*)d_ws;
    float* out = (float*)d_out;

    k0a<<<128, 256, 0, stream>>>(f1w, f2w, ws);
    k0b<<<256, 320, 0, stream>>>(f1w, f1b, fc1, ws);
    k0c<<<NBIG_PAD, 320, 0, stream>>>(f2w, f2b, invw, wemb, ws);
    a1<<<1024, 256, 0, stream>>>(feat, cond, f1b, f2b, ws);
    a2<<<1024, 256, 0, stream>>>(ws);
    kb<<<1024, 512, 0, stream>>>(feat, ws, out);
}

// Round 2
// 678.287 us; speedup vs baseline: 1.2673x; 1.2673x over previous
//
#include <hip/hip_runtime.h>
#include <hip/hip_bf16.h>
#include <stdint.h>

// Problem constants
#define BTOT 65536
#define KAUG 320
#define NBIG 2176
#define NBIG_PAD 2304
#define OUTD 384

typedef __attribute__((ext_vector_type(8))) short s16x8;
typedef __attribute__((ext_vector_type(4))) float f32x4;
typedef __attribute__((ext_vector_type(4))) uint32_t u32x4;

// workspace layout (bytes)
#define WS_WGT   0u                    // bf16 [512][64]   g-weights transposed [N][K]
#define WS_WFC   (64u*1024u)           // bf16 [256][320]  fc1 augmented, transposed
#define WS_WBIG  (224u*1024u)          // bf16 [2304][320] big augmented, transposed (padded rows zero)
#define WS_C1    (1664u*1024u)         // f32 [256]
#define WS_C2    (1665u*1024u)         // f32 [2304]
#define WS_ACT   (2u*1024u*1024u)      // bf16 [65536][320]  u_aug

__device__ __forceinline__ float bs2f(short s) {
    uint32_t u = ((uint32_t)(uint16_t)s) << 16; float f; __builtin_memcpy(&f, &u, 4); return f;
}
__device__ __forceinline__ short f2bs(float f) {
    __hip_bfloat16 h = __float2bfloat16(f); short s; __builtin_memcpy(&s, &h, 2); return s;
}
// XOR swizzle on byte offset within a row (row byte stride must be a multiple of 128; kb 16B-aligned)
__device__ __forceinline__ uint32_t swz(uint32_t row, uint32_t kb) { return kb ^ ((row & 7u) << 4); }

__device__ __forceinline__ f32x4 mfma16(s16x8 a, s16x8 b, f32x4 c) {
    asm volatile("v_mfma_f32_16x16x32_bf16 %0, %1, %2, %0" : "+v"(c) : "v"(a), "v"(b));
    return c;
}

// T14 async-stage helpers: chunk = [256 rows][64 k] bf16 from a [n][320]-bf16 weight array.
// issue: global -> regs (no LDS write, no vmcnt stall at issue site)
template <int NI>
__device__ __forceinline__ void issueB_t(const char* src, int tid, int base_n, int kc, u32x4 (&P)[NI]) {
#pragma unroll
    for (int i = 0; i < NI; ++i) {
        int gid = tid + i * 512; int row = gid >> 3, g = gid & 7;
        P[i] = *(const u32x4*)(src + (size_t)(base_n + row) * 640 + kc * 128 + g * 16);
    }
}
// commit: regs -> LDS (swizzled)
template <int NI>
__device__ __forceinline__ void commitB_t(char* dst, int tid, const u32x4 (&P)[NI]) {
#pragma unroll
    for (int i = 0; i < NI; ++i) {
        int gid = tid + i * 512; int row = gid >> 3, g = gid & 7;
        *(u32x4*)(dst + row * 128 + swz(row, g * 16)) = P[i];
    }
}

// ---------------- weight prep ----------------
// WgT[n][k]: n<256 -> film1_w[k][n] (g1), n>=256 -> film2_w[k][n-256] (g2)
__global__ __launch_bounds__(256) void k0a(const float* __restrict__ f1w, const float* __restrict__ f2w, char* ws) {
    int idx = blockIdx.x * 256 + threadIdx.x;   // 32768
    int n = idx >> 6, k = idx & 63;
    float v = (n < 256) ? f1w[k * 512 + n] : f2w[k * 512 + (n - 256)];
    ((short*)(ws + WS_WGT))[n * 64 + k] = f2bs(v);
}

// k0b: WfcT_aug[n][k] for n0..n0+15 (grid 16). LDS-staged aug GEMM.
__global__ __launch_bounds__(256) void k0b(const float* __restrict__ f1w, const float* __restrict__ f1b,
                                           const float* __restrict__ fc1, char* ws) {
    __shared__ float awt[256][65];   // [j][r] : f1w[r*512+256+j]
    __shared__ float fcc[256][16];   // [j][nl]: fc1[j*256 + n0+nl]
    const int tid = threadIdx.x;
    const int n0 = blockIdx.x * 16;
#pragma unroll 4
    for (int i = 0; i < 64; ++i) awt[tid][i] = f1w[i * 512 + 256 + tid];
#pragma unroll 4
    for (int i = 0; i < 16; ++i) {
        int idx = tid + i * 256; int j = idx >> 4, nl = idx & 15;
        fcc[j][nl] = fc1[j * 256 + n0 + nl];
    }
    __syncthreads();
    const int nl = tid & 15, rg = tid >> 4;
    float a0 = 0.f, a1v = 0.f, a2v = 0.f, a3v = 0.f;
    for (int j = 0; j < 256; ++j) {
        float wv = fcc[j][nl];
        a0 += awt[j][rg * 4 + 0] * wv; a1v += awt[j][rg * 4 + 1] * wv;
        a2v += awt[j][rg * 4 + 2] * wv; a3v += awt[j][rg * 4 + 3] * wv;
    }
    short* wfcT = (short*)(ws + WS_WFC);
    const int n = n0 + nl;
    wfcT[n * 320 + 256 + rg * 4 + 0] = f2bs(a0);
    wfcT[n * 320 + 256 + rg * 4 + 1] = f2bs(a1v);
    wfcT[n * 320 + 256 + rg * 4 + 2] = f2bs(a2v);
    wfcT[n * 320 + 256 + rg * 4 + 3] = f2bs(a3v);
#pragma unroll
    for (int p = 0; p < 16; ++p) { int k = rg * 16 + p; wfcT[n * 320 + k] = f2bs(fcc[k][nl]); }
    if (rg == 0) {
        float s = 0.f;
        for (int j = 0; j < 256; ++j) s += f1b[256 + j] * fcc[j][nl];
        ((float*)(ws + WS_C1))[n] = s;
    }
}

// k0c: WbigT_aug[n][k] for 16 cols/block (grid 137; last block zeroes padding).
__global__ __launch_bounds__(256) void k0c(const float* __restrict__ f2w, const float* __restrict__ f2b,
                                           const float* __restrict__ invw, const float* __restrict__ wemb, char* ws) {
    __shared__ float awt[256][65];   // [j][r] : f2w[r*512+256+j]
    __shared__ float wbc[256][16];   // [j][nl]: Wbig col
    const int tid = threadIdx.x;
    short* wbT = (short*)(ws + WS_WBIG);
    if (blockIdx.x == 136) {         // pad rows 2176..2303 + c2 pad
        for (int i = 0; i < 160; ++i) wbT[2176 * 320 + tid + i * 256] = 0;
        if (tid < 128) ((float*)(ws + WS_C2))[2176 + tid] = 0.f;
        return;
    }
    const int n0 = blockIdx.x * 16;
#pragma unroll 4
    for (int i = 0; i < 64; ++i) awt[tid][i] = f2w[i * 512 + 256 + tid];
#pragma unroll 4
    for (int i = 0; i < 16; ++i) {
        int idx = tid + i * 256; int j = idx >> 4, nl = idx & 15; int n = n0 + nl;
        wbc[j][nl] = (n < 128) ? invw[j * 128 + n] : wemb[j * 2048 + (n - 128)];
    }
    __syncthreads();
    const int nl = tid & 15, rg = tid >> 4;
    float a0 = 0.f, a1v = 0.f, a2v = 0.f, a3v = 0.f;
    for (int j = 0; j < 256; ++j) {
        float wv = wbc[j][nl];
        a0 += awt[j][rg * 4 + 0] * wv; a1v += awt[j][rg * 4 + 1] * wv;
        a2v += awt[j][rg * 4 + 2] * wv; a3v += awt[j][rg * 4 + 3] * wv;
    }
    const int n = n0 + nl;
    wbT[n * 320 + 256 + rg * 4 + 0] = f2bs(a0);
    wbT[n * 320 + 256 + rg * 4 + 1] = f2bs(a1v);
    wbT[n * 320 + 256 + rg * 4 + 2] = f2bs(a2v);
    wbT[n * 320 + 256 + rg * 4 + 3] = f2bs(a3v);
#pragma unroll
    for (int p = 0; p < 16; ++p) { int k = rg * 16 + p; wbT[n * 320 + k] = f2bs(wbc[k][nl]); }
    if (rg == 0) {
        float s = 0.f;
        for (int j = 0; j < 256; ++j) s += f2b[256 + j] * wbc[j][nl];
        ((float*)(ws + WS_C2))[n] = s;
    }
}

// ---------------- af: fused FiLM1 + fc1 + FiLM2 -> u_aug (t, g2 stay in LDS) ----------------
__global__ __launch_bounds__(512) void af(const float* __restrict__ feat, const float* __restrict__ cond,
                                          const float* __restrict__ f1b, const float* __restrict__ f2b, char* ws) {
    __shared__ short sCond[64 * 64];       // stride 128 B, swizzled
    __shared__ short sT[64 * 256];         // stride 512 B, swizzled (phase-2 A, k<256)
    __shared__ short sG2[64 * 256];        // stride 512 B, swizzled
    __shared__ short sBuf[2][256 * 64];    // phase 2 B chunks; phase 1: sWg aliased over both (512x64)
    const int tid = threadIdx.x;
    const int r0 = blockIdx.x * 64;
    short* actw = (short*)(ws + WS_ACT);
    const char* wfc = ws + WS_WFC;

    u32x4 pfA[4], pfB[4];
    issueB_t(wfc, tid, 0, 0, pfA);         // fire Wfc chunks 0,1 early; latency hides under phase 1
    issueB_t(wfc, tid, 0, 1, pfB);

    {   // cond -> sCond (swizzled bf16) + dual-store into act cols 256..319
        int row = tid >> 3, g = tid & 7;
        const float* src = cond + (size_t)(r0 + row) * 64 + g * 8;
        s16x8 p;
#pragma unroll
        for (int j = 0; j < 8; ++j) p[j] = f2bs(src[j]);
        *(s16x8*)((char*)sCond + row * 128 + swz(row, g * 16)) = p;
        *(s16x8*)(actw + (size_t)(r0 + row) * 320 + 256 + g * 8) = p;
    }
    {   // WgT -> sWg (aliased over sBuf)
        const char* wgt = ws + WS_WGT;
        char* sWg = (char*)sBuf;
#pragma unroll
        for (int i = 0; i < 8; ++i) {
            int gid = tid + i * 512; int row = gid >> 3, g = gid & 7;
            u32x4 v = *(const u32x4*)(wgt + row * 128 + g * 16);
            *(u32x4*)(sWg + row * 128 + swz(row, g * 16)) = v;
        }
    }
    __syncthreads();

    const int w = tid >> 6, l = tid & 63, lr = l & 15, lk = l >> 4;
    // cond A-frags (also reused in phase 2, kc==4)
    s16x8 caf[4][2];
#pragma unroll
    for (int fm = 0; fm < 4; ++fm)
#pragma unroll
        for (int ks = 0; ks < 2; ++ks) {
            int row = fm * 16 + lr; uint32_t kb = (ks * 32 + lk * 8) * 2;
            caf[fm][ks] = *(const s16x8*)((char*)sCond + row * 128 + swz(row, kb));
        }
    {   // phase 1: g = cond @ WgT, 8 waves x 64 cols = 512 cols
        const char* sWg = (const char*)sBuf;
        const int nw = w * 64;
        f32x4 acc[4][4] = {};
        __builtin_amdgcn_s_setprio(1);
#pragma unroll
        for (int ks = 0; ks < 2; ++ks) {
            uint32_t kb = (ks * 32 + lk * 8) * 2;
            s16x8 bf[4];
#pragma unroll
            for (int fn = 0; fn < 4; ++fn) { int row = nw + fn * 16 + lr;
                bf[fn] = *(const s16x8*)(sWg + row * 128 + swz(row, kb)); }
#pragma unroll
            for (int fm = 0; fm < 4; ++fm)
#pragma unroll
                for (int fn = 0; fn < 4; ++fn)
                    acc[fm][fn] = mfma16(caf[fm][ks], bf[fn], acc[fm][fn]);
        }
        __builtin_amdgcn_s_setprio(0);
        asm volatile("s_nop 7\n\ts_nop 7");
        if (nw < 256) {   // g1 -> t = feat*g1 -> sT
#pragma unroll
            for (int fm = 0; fm < 4; ++fm)
#pragma unroll
                for (int fn = 0; fn < 4; ++fn) {
                    int c = nw + fn * 16 + lr;
                    float bias = f1b[c];
#pragma unroll
                    for (int ri = 0; ri < 4; ++ri) {
                        int row = fm * 16 + lk * 4 + ri;
                        float g1 = acc[fm][fn][ri] + bias;
                        float t = feat[(size_t)(r0 + row) * 512 + c] * g1;
                        *(short*)((char*)sT + row * 512 + (((uint32_t)(c * 2)) ^ ((row & 7u) << 4))) = f2bs(t);
                    }
                }
        } else {          // g2 -> sG2
#pragma unroll
            for (int fm = 0; fm < 4; ++fm)
#pragma unroll
                for (int fn = 0; fn < 4; ++fn) {
                    int cg = nw - 256 + fn * 16 + lr;
                    float bias = f2b[cg];
#pragma unroll
                    for (int ri = 0; ri < 4; ++ri) {
                        int row = fm * 16 + lk * 4 + ri;
                        *(short*)((char*)sG2 + row * 512 + (((uint32_t)(cg * 2)) ^ ((row & 7u) << 4))) = f2bs(acc[fm][fn][ri] + bias);
                    }
                }
        }
    }
    __syncthreads();                       // sWg fully consumed; sT/sG2 ready
    commitB_t((char*)sBuf[0], tid, pfA);   // Wfc chunk 0 (loads returned long ago)
    issueB_t(wfc, tid, 0, 2, pfA);
    __syncthreads();

    // phase 2: s = [t|cond] @ WfcT_aug, K=320 as 5 chunks of 64
    const int wm = w >> 2, wn = w & 3;     // 2x4 waves: 32 rows x 64 cols each
    f32x4 acc2[2][4] = {};
    for (int kc = 0; kc < 5; ++kc) {
        const int pr = (kc + 1) & 1;
        if (kc <= 3) { if (pr == 0) commitB_t((char*)sBuf[0], tid, pfA); else commitB_t((char*)sBuf[1], tid, pfB); }
        if (kc <= 1) { if (pr == 0) issueB_t(wfc, tid, 0, kc + 3, pfA); else issueB_t(wfc, tid, 0, kc + 3, pfB); }
        const char* bbuf = (const char*)sBuf[kc & 1];
        __builtin_amdgcn_s_setprio(1);
#pragma unroll
        for (int ks = 0; ks < 2; ++ks) {
            uint32_t kb = (ks * 32 + lk * 8) * 2;
            s16x8 a2f[2], b2f[4];
#pragma unroll
            for (int fm = 0; fm < 2; ++fm) {
                int row = wm * 32 + fm * 16 + lr;
                if (kc < 4) a2f[fm] = *(const s16x8*)((char*)sT + row * 512 + swz(row, kc * 128 + kb));
                else        a2f[fm] = caf[wm * 2 + fm][ks];
            }
#pragma unroll
            for (int fn = 0; fn < 4; ++fn) { int row = wn * 64 + fn * 16 + lr;
                b2f[fn] = *(const s16x8*)(bbuf + row * 128 + swz(row, kb)); }
#pragma unroll
            for (int fm = 0; fm < 2; ++fm)
#pragma unroll
                for (int fn = 0; fn < 4; ++fn)
                    acc2[fm][fn] = mfma16(a2f[fm], b2f[fn], acc2[fm][fn]);
        }
        __builtin_amdgcn_s_setprio(0);
        __syncthreads();
    }
    asm volatile("s_nop 7\n\ts_nop 7");
    const float* c1 = (const float*)(ws + WS_C1);
#pragma unroll
    for (int fm = 0; fm < 2; ++fm)
#pragma unroll
        for (int fn = 0; fn < 4; ++fn) {
            int c = wn * 64 + fn * 16 + lr;
            float cc1 = c1[c];
#pragma unroll
            for (int ri = 0; ri < 4; ++ri) {
                int row = wm * 32 + fm * 16 + lk * 4 + ri;
                float s = acc2[fm][fn][ri] + cc1;
                float g2v = bs2f(*(const short*)((char*)sG2 + row * 512 + (((uint32_t)(c * 2)) ^ ((row & 7u) << 4))));
                actw[(size_t)(r0 + row) * 320 + c] = f2bs(s * g2v);
            }
        }
}

// ---------------- kb: out_all = u_aug @ WbigT_aug (K=320, N=2304 padded) + fused einsum ----------------
__global__ __launch_bounds__(512) void kb(const float* __restrict__ feat, char* ws, float* __restrict__ out) {
    __shared__ short sA[64 * 320];        // ROWB 640, full K resident
    __shared__ short sB[2][256 * 64];     // ROWB 128, double-buffered chunks
    __shared__ short sW[64 * 256];        // ROWB 512, w-tile for einsum
    const int tid = threadIdx.x;
    const int r0 = blockIdx.x * 64;
    const short* actw = (const short*)(ws + WS_ACT);
    const char* wbig = ws + WS_WBIG;
    const float* c2 = (const float*)(ws + WS_C2);

    // einsum persistent state: thread -> (row er, slot); slots 0..2 = y1 d, 3..7 = y2 d
    const int er = tid >> 3, slot = tid & 7;
    const int region = (slot < 3) ? 1 : 2;
    const int d = (slot < 3) ? slot : slot - 3;
    float y[32];
    float x[32];
    {
        const float* xb = feat + (size_t)(r0 + er) * 512 + 256 + ((region == 1) ? 0 : 96);
        const int stride = (region == 1) ? 3 : 5;
#pragma unroll
        for (int i = 0; i < 32; ++i) x[i] = xb[i * stride + d];
#pragma unroll
        for (int o = 0; o < 32; ++o) y[o] = 0.f;
    }

    // T14 2-deep pipeline: fire chunks 0,1 then stage sA (latency cover), commit 0, fire 2
    u32x4 pfA[4], pfB[4];
    issueB_t(wbig, tid, 0, 0, pfA);
    issueB_t(wbig, tid, 0, 1, pfB);
#pragma unroll
    for (int i = 0; i < 5; ++i) {
        int gid = tid + i * 512; int row = gid / 40, g = gid % 40;
        u32x4 v = *(const u32x4*)(actw + (size_t)(r0 + row) * 320 + g * 8);
        *(u32x4*)((char*)sA + row * 640 + swz(row, g * 16)) = v;
    }
    commitB_t((char*)sB[0], tid, pfA);
    issueB_t(wbig, tid, 0, 2, pfA);
    __syncthreads();

    const int w = tid >> 6, l = tid & 63, lr = l & 15, lk = l >> 4;
    const int wm = w >> 2, wn = w & 3;    // wave tile: rows wm*32..+32, cols wn*64..+64 within N-tile of 256
    const float norm = 0.17677669529663687f;

    int ntI = 0, kcI = 3;                 // next chunk to issue = 3
    for (int nt = 0; nt < 9; ++nt) {
        const int n0 = nt * 256;
        f32x4 acc[2][4] = {};
        for (int kc = 0; kc < 5; ++kc) {
            const int q = nt * 5 + kc;
            const int pr = (q + 1) & 1;
            if (q <= 43) { if (pr == 0) commitB_t((char*)sB[0], tid, pfA); else commitB_t((char*)sB[1], tid, pfB); }
            if (q <= 41) {
                if (pr == 0) issueB_t(wbig, tid, ntI * 256, kcI, pfA); else issueB_t(wbig, tid, ntI * 256, kcI, pfB);
                if (++kcI == 5) { kcI = 0; ++ntI; }
            }
            const char* bbuf = (const char*)sB[q & 1];
            __builtin_amdgcn_s_setprio(1);
#pragma unroll
            for (int ks = 0; ks < 2; ++ks) {
                uint32_t kb = (ks * 32 + lk * 8) * 2;
                s16x8 afr[2], bf[4];
#pragma unroll
                for (int fm = 0; fm < 2; ++fm) { int row = wm * 32 + fm * 16 + lr;
                    afr[fm] = *(const s16x8*)((char*)sA + row * 640 + swz(row, kc * 128 + kb)); }
#pragma unroll
                for (int fn = 0; fn < 4; ++fn) { int row = wn * 64 + fn * 16 + lr;
                    bf[fn] = *(const s16x8*)(bbuf + row * 128 + swz(row, kb)); }
#pragma unroll
                for (int fm = 0; fm < 2; ++fm)
#pragma unroll
                    for (int fn = 0; fn < 4; ++fn)
                        acc[fm][fn] = mfma16(afr[fm], bf[fn], acc[fm][fn]);
            }
            __builtin_amdgcn_s_setprio(0);
            __syncthreads();
        }
        asm volatile("s_nop 7\n\ts_nop 7");
        // epilogue: scalar cols -> out directly, w cols -> sW (+c2), pad cols dropped
#pragma unroll
        for (int fm = 0; fm < 2; ++fm)
#pragma unroll
            for (int fn = 0; fn < 4; ++fn) {
                int c = n0 + wn * 64 + fn * 16 + lr;
                float cc2 = c2[c];
#pragma unroll
                for (int ri = 0; ri < 4; ++ri) {
                    int rl = wm * 32 + fm * 16 + lk * 4 + ri;
                    float v = acc[fm][fn][ri] + cc2;
                    if (c < 128) out[(size_t)(r0 + rl) * OUTD + c] = v;
                    else if (c < NBIG) {
                        int cl = wn * 64 + fn * 16 + lr;
                        *(short*)((char*)sW + rl * 512 + ((uint32_t)(cl * 2) ^ ((rl & 7u) << 4))) = f2bs(v);
                    }
                }
            }
        __syncthreads();
        // fused einsum on this tile's w columns
        for (int islot = 0; islot < 8; ++islot) {
            int cb = n0 + islot * 32;
            if (cb < 128 || cb >= NBIG) continue;
            int treg = (cb < 1152) ? 1 : 2;
            if (treg != region) continue;
            int i = (cb - ((treg == 1) ? 128 : 1152)) >> 5;
            float xv = x[i];
#pragma unroll
            for (int og = 0; og < 4; ++og) {
                uint32_t clb = (uint32_t)(islot * 64 + og * 16);
                s16x8 wv = *(const s16x8*)((const char*)sW + er * 512 + (clb ^ ((er & 7u) << 4)));
#pragma unroll
                for (int j = 0; j < 8; ++j) y[og * 8 + j] += bs2f(wv[j]) * xv;
            }
        }
        __syncthreads();
    }
    // final equivariant writes
    float* orow = out + (size_t)(r0 + er) * OUTD;
    if (region == 1) { for (int o = 0; o < 32; ++o) orow[128 + o * 3 + d] = y[o] * norm; }
    else             { for (int o = 0; o < 32; ++o) orow[224 + o * 5 + d] = y[o] * norm; }
}

extern "C" void kernel_launch(void* const* d_in, const int* in_sizes, int n_in,
                              void* d_out, int out_size, void* d_ws, size_t ws_size,
                              hipStream_t stream) {
    (void)in_sizes; (void)n_in; (void)out_size; (void)ws_size;
    const float* feat = (const float*)d_in[0];
    const float* cond = (const float*)d_in[1];
    const float* f1w  = (const float*)d_in[2];
    const float* f1b  = (const float*)d_in[3];
    const float* fc1  = (const float*)d_in[4];
    const float* f2w  = (const float*)d_in[5];
    const float* f2b  = (const float*)d_in[6];
    const float* invw = (const float*)d_in[7];
    const float* wemb = (const float*)d_in[8];
    char* ws = (char*)d_ws;
    float* out = (float*)d_out;

    k0a<<<128, 256, 0, stream>>>(f1w, f2w, ws);
    k0b<<<16, 256, 0, stream>>>(f1w, f1b, fc1, ws);
    k0c<<<137, 256, 0, stream>>>(f2w, f2b, invw, wemb, ws);
    af<<<1024, 512, 0, stream>>>(feat, cond, f1b, f2b, ws);
    kb<<<1024, 512, 0, stream>>>(feat, ws, out);
}